// Round 13
// baseline (519.428 us; speedup 1.0000x reference)
//
#include <hip/hip_runtime.h>
#include <hip/hip_bf16.h>
#include <hip/hip_fp16.h>

typedef __hip_bfloat16 bf16;
typedef unsigned short u16;
typedef short bfrag __attribute__((ext_vector_type(8)));   // 8 bf16 = 4 VGPRs
typedef float f32x4 __attribute__((ext_vector_type(4)));
typedef unsigned u32x4 __attribute__((ext_vector_type(4))); // native vec for nt-store

#define NGRAPH 512
#define BN_EPS 1e-5f
#define NBUCK 64

__device__ __forceinline__ float b2f(bf16 x) { return __bfloat162float(x); }
__device__ __forceinline__ float bf_lo(unsigned u) { return __uint_as_float(u << 16); }
__device__ __forceinline__ float bf_hi(unsigned u) { return __uint_as_float(u & 0xffff0000u); }
__device__ __forceinline__ u16 f2u(float v) {
    bf16 t = __float2bfloat16(v);
    u16 r; __builtin_memcpy(&r, &t, 2); return r;
}

__device__ __forceinline__ float load_f(const void* p, int i, int isbf16) {
    if (isbf16) {
        unsigned short u = ((const unsigned short*)p)[i];
        return __uint_as_float(((unsigned int)u) << 16);
    }
    return ((const float*)p)[i];
}

// ---------------- dtype detection ----------------
__global__ void detect_dtype(const void* __restrict__ x, int* __restrict__ flag) {
    int lane = threadIdx.x & 63;
    unsigned short u = ((const unsigned short*)x)[2 * lane];
    float f = __uint_as_float(((unsigned int)u) << 16);
    int crazy = (!(fabsf(f) <= 1024.0f)) ? 1 : 0;
    unsigned long long m = __ballot(crazy);
    if (threadIdx.x == 0) *flag = (m == 0ULL) ? 1 : 0;   // 1 = bf16, 0 = fp32
}

// ---------------- convert x -> bf16, slice-major [2][npad][32] -------------
__global__ void cvt_bf_s(const void* __restrict__ in, u16* __restrict__ out,
                         int n, int npad, const int* __restrict__ flag) {
    int i = blockIdx.x * blockDim.x + threadIdx.x;
    if (i >= n * 64) return;
    int node = i >> 6, f = i & 63;
    out[((size_t)(f >> 5) * npad + node) * 32 + (f & 31)] = f2u(load_f(in, i, *flag));
}

// ---------------- repack W[K][N] into MFMA B-fragment order ----------------
__global__ void repack_w(const void* __restrict__ W, u16* __restrict__ out,
                         int Kd, int Nd, const int* __restrict__ flag) {
    int t = blockIdx.x * blockDim.x + threadIdx.x;
    if (t >= Kd * Nd) return;
    int isbf = *flag;
    int j = t & 7;
    int lane = (t >> 3) & 63;
    int tile = t >> 9;
    int NT = Nd / 16;
    int nt = tile % NT, kt = tile / NT;
    int k = kt * 32 + (lane >> 4) * 8 + j;
    int nn = nt * 16 + (lane & 15);
    out[t] = f2u(load_f(W, k * Nd + nn, isbf));
}

// ---------------- all three BN foldings in one dispatch --------------------
__device__ __forceinline__ void fold_one(const void* b, const void* g, const void* be,
                                         const void* m, const void* v,
                                         float* S, float* T, int f, int isbf) {
    float bb = load_f(b, f, isbf), gg = load_f(g, f, isbf);
    float bee = load_f(be, f, isbf), mm = load_f(m, f, isbf);
    float vv = load_f(v, f, isbf);
    float s = gg * rsqrtf(vv + BN_EPS);
    S[f] = s;
    T[f] = (bb - mm) * s + bee;
}

__global__ void fold_bn_all(
    const void* b1, const void* g1, const void* be1, const void* m1, const void* v1,
    const void* b2, const void* g2, const void* be2, const void* m2, const void* v2,
    const void* b3, const void* g3, const void* be3, const void* m3, const void* v3,
    float* S1, float* T1, float* S2, float* T2, float* S3, float* T3,
    const int* __restrict__ flag) {
    int t = blockIdx.x * blockDim.x + threadIdx.x;
    int isbf = *flag;
    if (t < 128) fold_one(b1, g1, be1, m1, v1, S1, T1, t, isbf);
    else if (t < 384) fold_one(b2, g2, be2, m2, v2, S2, T2, t - 128, isbf);
    else if (t < 640) fold_one(b3, g3, be3, m3, v3, S3, T3, t - 384, isbf);
}

// ---------------- CSR build (padded segments + packed edge records) --------
__global__ void init_csr(int* __restrict__ deg, int* __restrict__ total,
                         int* __restrict__ bcnt, int n) {
    int i = blockIdx.x * blockDim.x + threadIdx.x;
    if (i < n) deg[i] = 0;
    if (i < NBUCK) bcnt[i] = 0;
    if (i == 0) *total = 0;
}

__global__ void count_deg_i(const int* __restrict__ dst, int* __restrict__ deg, int e) {
    int i = blockIdx.x * blockDim.x + threadIdx.x;
    if (i < e) atomicAdd(&deg[dst[i]], 1);
}

// Reserve 8-padded CSR segment per node; LDS degree histogram (divergent
// global atomics serialize — r9 lesson); pad entries filled here too.
__global__ void reserve_rows(const int* __restrict__ deg, int* __restrict__ row_start,
                             int* __restrict__ cursor, float* __restrict__ dis,
                             unsigned* __restrict__ csrw,
                             int* __restrict__ total, int* __restrict__ bcnt, int n) {
    __shared__ int lh[NBUCK];
    int tid = threadIdx.x;
    if (tid < NBUCK) lh[tid] = 0;
    __syncthreads();
    int i = blockIdx.x * blockDim.x + tid;
    if (i < n) {
        int d = deg[i];
        int dpad = (d + 7) & ~7;
        int s = atomicAdd(total, dpad);     // uniform address -> wave-coalesced
        row_start[i] = s;
        cursor[i] = s;
        dis[i] = rsqrtf((float)(d + 1));    // +1 self-loop
        atomicAdd(&lh[min(d, NBUCK - 1)], 1);
        unsigned val = (unsigned)(i & 0xffff);   // pad: src=self, norm=+0
        for (int k = d; k < dpad; k++) csrw[s + k] = val;
    }
    __syncthreads();
    if (tid < NBUCK) {
        int c = lh[tid];
        if (c) atomicAdd(&bcnt[tid], c);
    }
}

__global__ void bucket_prefix(const int* __restrict__ bcnt, int* __restrict__ bcur) {
    if (threadIdx.x == 0 && blockIdx.x == 0) {
        int acc = 0;
        for (int i = 0; i < NBUCK; i++) { bcur[i] = acc; acc += bcnt[i]; }
    }
}

// Ranked scatter emitting packed per-node records {node, start, deg, -}.
__global__ void bucket_scatter(const int* __restrict__ deg, const int* __restrict__ rowst,
                               int* __restrict__ bcur, uint4* __restrict__ ninfo, int n) {
    __shared__ int lh[NBUCK];
    __shared__ int lbase[NBUCK];
    int tid = threadIdx.x;
    if (tid < NBUCK) lh[tid] = 0;
    __syncthreads();
    int i = blockIdx.x * blockDim.x + tid;
    int b = 0, lr = 0;
    if (i < n) {
        b = min(deg[i], NBUCK - 1);
        lr = atomicAdd(&lh[b], 1);          // LDS local rank
    }
    __syncthreads();
    if (tid < NBUCK) {
        int c = lh[tid];
        lbase[tid] = c ? atomicAdd(&bcur[tid], c) : 0;
    }
    __syncthreads();
    if (i < n) ninfo[lbase[b] + lr] = make_uint4(i, rowst[i], deg[i], 0);
}

// Pack {u16 src, fp16 norm} per edge; norm computed once here.
__global__ void scatter_edges(const int* __restrict__ src, const int* __restrict__ dst,
                              const float* __restrict__ dis, int* __restrict__ cursor,
                              unsigned* __restrict__ csrw, int e) {
    int i = blockIdx.x * blockDim.x + threadIdx.x;
    if (i >= e) return;
    int s = src[i], dt = dst[i];
    int pos = atomicAdd(&cursor[dt], 1);
    float nw = dis[s] * dis[dt];
    unsigned short h = __half_as_ushort(__float2half(nw));
    csrw[pos] = (unsigned)(s & 0xffff) | ((unsigned)h << 16);
}

// ---------------- XCD-sliced CSR aggregation v4 ----------------------------
// 4 lanes/node x 16B loads, 16 nodes/wave. Non-temporal csrw loads and AG
// stores keep the per-pass L2 working set ~= the 3.2MB feature slice
// (r11 showed ~11MB WS thrashing the 4MB XCD L2 -> 2x feature refetch).
template <int NSLICE>
__global__ __launch_bounds__(256) void csr_agg_s4(
    const uint4* __restrict__ ninfo, const unsigned* __restrict__ csrw,
    const u16* __restrict__ hs, u16* __restrict__ AG, int n, int npad) {
    constexpr int F = NSLICE * 32;
    int slice = blockIdx.x % NSLICE;
    int nb = blockIdx.x / NSLICE;
    int lane = threadIdx.x & 63;
    int wv = threadIdx.x >> 6;
    int sub = lane >> 2, ls = lane & 3;     // 16 nodes/wave, 4 lanes/node
    int oidx = nb * 64 + wv * 16 + sub;
    if (oidx >= n) return;
    uint4 nf = ninfo[oidx];                 // contiguous 16B records
    int node = (int)nf.x;
    int start = (int)nf.y;
    int d = (int)nf.z;
    int dpad = (d + 7) & ~7;
    float dd = 1.0f / (float)(d + 1);       // dis^2 for the self-loop
    const u16* __restrict__ base = hs + (size_t)slice * npad * 32;
    const int fo = ls * 8;                  // 8 features per lane

    float a0, a1, a2, a3, a4, a5, a6, a7;
    {
        u32x4 u = *(const u32x4*)(base + (size_t)node * 32 + fo);
        a0 = bf_lo(u.x) * dd; a1 = bf_hi(u.x) * dd;
        a2 = bf_lo(u.y) * dd; a3 = bf_hi(u.y) * dd;
        a4 = bf_lo(u.z) * dd; a5 = bf_hi(u.z) * dd;
        a6 = bf_lo(u.w) * dd; a7 = bf_hi(u.w) * dd;
    }

    const unsigned* __restrict__ ep = csrw + start;
    for (int k = 0; k < dpad; k += 8) {
        unsigned m[8];
#pragma unroll
        for (int j = 0; j < 8; j++)
            m[j] = __builtin_nontemporal_load(ep + k + j);   // streamed, no L2 alloc
        float w[8];
        u32x4 q[8];
#pragma unroll
        for (int j = 0; j < 8; j++) {
            int s = (int)(m[j] & 0xffffu);
            w[j] = __half2float(__ushort_as_half((unsigned short)(m[j] >> 16)));
            q[j] = *(const u32x4*)(base + (size_t)s * 32 + fo);
        }
#pragma unroll
        for (int j = 0; j < 8; j++) {
            a0 += w[j] * bf_lo(q[j].x); a1 += w[j] * bf_hi(q[j].x);
            a2 += w[j] * bf_lo(q[j].y); a3 += w[j] * bf_hi(q[j].y);
            a4 += w[j] * bf_lo(q[j].z); a5 += w[j] * bf_hi(q[j].z);
            a6 += w[j] * bf_lo(q[j].w); a7 += w[j] * bf_hi(q[j].w);
        }
    }
    u32x4 o;
    o.x = (unsigned)f2u(a0) | ((unsigned)f2u(a1) << 16);
    o.y = (unsigned)f2u(a2) | ((unsigned)f2u(a3) << 16);
    o.z = (unsigned)f2u(a4) | ((unsigned)f2u(a5) << 16);
    o.w = (unsigned)f2u(a6) | ((unsigned)f2u(a7) << 16);
    __builtin_nontemporal_store(o, (u32x4*)(AG + (size_t)node * F + slice * 32 + fo));
}

// ---------------- MFMA GEMM + fused BN + ReLU ------------------------------
template <int K, int N, int NSLICE_OUT>
__global__ __launch_bounds__(256) void mfma_gemm_bn(
    const u16* __restrict__ A, const u16* __restrict__ Wrep,
    const float* __restrict__ S, const float* __restrict__ T,
    u16* __restrict__ C, int M, int npad) {
    constexpr int KP = K + 8;
    constexpr int NT = N / 16;
    constexpr int KT = K / 32;
    __shared__ u16 Alds[64 * KP];
    const int m0 = blockIdx.x * 64;
    const int tid = threadIdx.x;
    for (int c = tid; c < 64 * (K / 8); c += 256) {
        int r = c / (K / 8), kc = c % (K / 8);
        uint4 v = *(const uint4*)(A + (size_t)(m0 + r) * K + kc * 8);
        *(uint4*)(&Alds[r * KP + kc * 8]) = v;
    }
    __syncthreads();
    const int wv = tid >> 6, lane = tid & 63;
    const int mrow = lane & 15;
    const int kb = lane >> 4;
    f32x4 acc[NT];
#pragma unroll
    for (int nt = 0; nt < NT; nt++) acc[nt] = (f32x4){0.f, 0.f, 0.f, 0.f};
#pragma unroll
    for (int kt = 0; kt < KT; kt++) {
        bfrag a = *(const bfrag*)(&Alds[(wv * 16 + mrow) * KP + kt * 32 + kb * 8]);
#pragma unroll
        for (int nt = 0; nt < NT; nt++) {
            bfrag b = *(const bfrag*)(Wrep + ((size_t)(kt * NT + nt) * 64 + lane) * 8);
            acc[nt] = __builtin_amdgcn_mfma_f32_16x16x32_bf16(a, b, acc[nt], 0, 0, 0);
        }
    }
#pragma unroll
    for (int nt = 0; nt < NT; nt++) {
        int f = nt * 16 + mrow;
        float s = S[f];
        float t = T[f];
#pragma unroll
        for (int r = 0; r < 4; r++) {
            int row = m0 + wv * 16 + kb * 4 + r;
            if (row < M) {
                u16 val = f2u(fmaxf(acc[nt][r] * s + t, 0.0f));
                if (NSLICE_OUT > 0)
                    C[((size_t)(f >> 5) * npad + row) * 32 + (f & 31)] = val;
                else
                    C[(size_t)row * N + f] = val;
            }
        }
    }
}

// ---------------- pooling ----------------
__global__ void init_pool(float* __restrict__ psum, float* __restrict__ pmax,
                          int* __restrict__ pcnt) {
    int i = blockIdx.x * blockDim.x + threadIdx.x;
    if (i < NGRAPH * 256) { psum[i] = 0.f; pmax[i] = 0.f; }
    if (i < NGRAPH) pcnt[i] = 0;
}

#define POOL_NC 64
__global__ __launch_bounds__(256) void pool_seg(
    const u16* __restrict__ h, const int* __restrict__ batch,
    float* __restrict__ psum, float* __restrict__ pmax,
    int* __restrict__ pcnt, int n) {
    int wid = (int)(((size_t)blockIdx.x * blockDim.x + threadIdx.x) >> 6);
    int lane = threadIdx.x & 63;
    int n0 = wid * POOL_NC;
    if (n0 >= n) return;
    int n1 = min(n0 + POOL_NC, n);

    float sum[4] = {0.f, 0.f, 0.f, 0.f};
    float mx[4] = {0.f, 0.f, 0.f, 0.f};
    int cnt = 0;
    int gcur = batch[n0];

    uint2 u_next = *(const uint2*)(h + (size_t)n0 * 256 + lane * 4);
    int g_next = gcur;

    for (int node = n0; node < n1; node++) {
        uint2 u = u_next;
        int g = g_next;
        if (node + 1 < n1) {
            u_next = *(const uint2*)(h + (size_t)(node + 1) * 256 + lane * 4);
            g_next = batch[node + 1];
        }
        if (g != gcur) {
#pragma unroll
            for (int c = 0; c < 4; c++) {
                atomicAdd(&psum[gcur * 256 + lane * 4 + c], sum[c]);
                atomicMax((int*)&pmax[gcur * 256 + lane * 4 + c], __float_as_int(mx[c]));
                sum[c] = 0.f; mx[c] = 0.f;
            }
            if (lane == 0) atomicAdd(&pcnt[gcur], cnt);
            cnt = 0;
            gcur = g;
        }
        float v0 = bf_lo(u.x), v1 = bf_hi(u.x), v2 = bf_lo(u.y), v3 = bf_hi(u.y);
        sum[0] += v0; sum[1] += v1; sum[2] += v2; sum[3] += v3;
        mx[0] = fmaxf(mx[0], v0); mx[1] = fmaxf(mx[1], v1);
        mx[2] = fmaxf(mx[2], v2); mx[3] = fmaxf(mx[3], v3);
        cnt++;
    }
#pragma unroll
    for (int c = 0; c < 4; c++) {
        atomicAdd(&psum[gcur * 256 + lane * 4 + c], sum[c]);
        atomicMax((int*)&pmax[gcur * 256 + lane * 4 + c], __float_as_int(mx[c]));
    }
    if (lane == 0) atomicAdd(&pcnt[gcur], cnt);
}

__global__ void build_z(const float* __restrict__ psum, const float* __restrict__ pmax,
                        const int* __restrict__ pcnt, float* __restrict__ z) {
    int i = blockIdx.x * blockDim.x + threadIdx.x;
    if (i >= NGRAPH * 256) return;
    int g = i >> 8, f = i & 255;
    float c = (float)max(pcnt[g], 1);
    z[g * 512 + f] = psum[i] / c;
    z[g * 512 + 256 + f] = pmax[i];
}

// ---------------- MLP GEMM (block per row) ----------------
template <int K, int NOUT, bool GELU>
__global__ void mlp_gemm(const float* __restrict__ A, const void* __restrict__ W,
                         const void* __restrict__ bias, float* __restrict__ C,
                         const int* __restrict__ flag) {
    __shared__ float a[K];
    int row = blockIdx.x;
    for (int idx = threadIdx.x; idx < K; idx += blockDim.x) a[idx] = A[row * K + idx];
    __syncthreads();
    int col = threadIdx.x;
    if (col < NOUT) {
        int isbf = *flag;
        float acc = load_f(bias, col, isbf);
        if (isbf) {
            const bf16* w = (const bf16*)W;
            for (int k = 0; k < K; k++) acc += a[k] * b2f(w[k * NOUT + col]);
        } else {
            const float* w = (const float*)W;
            for (int k = 0; k < K; k++) acc += a[k] * w[k * NOUT + col];
        }
        if (GELU) acc = 0.5f * acc * (1.0f + erff(acc * 0.70710678118654752f));
        C[row * NOUT + col] = acc;
    }
}

__global__ void write_out(const float* __restrict__ in, void* __restrict__ out,
                          int n, const int* __restrict__ flag) {
    int i = blockIdx.x * blockDim.x + threadIdx.x;
    if (i >= n) return;
    if (*flag) ((bf16*)out)[i] = __float2bfloat16(in[i]);
    else       ((float*)out)[i] = in[i];
}

extern "C" void kernel_launch(void* const* d_in, const int* in_sizes, int n_in,
                              void* d_out, int out_size, void* d_ws, size_t ws_size,
                              hipStream_t stream) {
    const void* x     = d_in[0];
    const int*  ei    = (const int*)d_in[1];
    const int*  batch = (const int*)d_in[2];
    const void *W1 = d_in[3],  *b1 = d_in[4],  *g1 = d_in[5],  *be1 = d_in[6],  *m1 = d_in[7],  *v1 = d_in[8];
    const void *W2 = d_in[9],  *b2 = d_in[10], *g2 = d_in[11], *be2 = d_in[12], *m2 = d_in[13], *v2 = d_in[14];
    const void *W3 = d_in[15], *b3 = d_in[16], *g3 = d_in[17], *be3 = d_in[18], *m3 = d_in[19], *v3 = d_in[20];
    const void *Wm1 = d_in[21], *bm1 = d_in[22];
    const void *Wm2 = d_in[23], *bm2 = d_in[24];
    const void *Wm3 = d_in[25], *bm3 = d_in[26];

    const int n = in_sizes[0] / 64;     // 50000
    const int E = in_sizes[1] / 2;      // 800000
    const int* src = ei;
    const int* dst = ei + E;
    const int npad = (n + 63 + 64) & ~63;

    size_t off = 0;
    auto carve = [&](size_t bytes) {
        void* p = (char*)d_ws + off;
        off += (bytes + 255) & ~(size_t)255;
        return p;
    };
    int*      flag  = (int*)carve(4);
    int*      total = (int*)carve(4);
    int*      bcnt  = (int*)carve(NBUCK * 4);
    int*      bcur  = (int*)carve(NBUCK * 4);
    float*    dis   = (float*)carve((size_t)n * 4);
    int*      deg_i = (int*)carve((size_t)n * 4);
    int*      rowst = (int*)carve((size_t)n * 4);
    int*      curs  = (int*)carve((size_t)n * 4);
    uint4*    ninfo = (uint4*)carve((size_t)n * 16);
    unsigned* csrw  = (unsigned*)carve(((size_t)E + 8 * (size_t)n) * 4);
    u16*      xs    = (u16*)carve((size_t)npad * 64 * 2);
    u16*      Hs    = (u16*)carve((size_t)npad * 256 * 2);
    u16*      AG    = (u16*)carve((size_t)npad * 256 * 2);
    u16*      H     = (u16*)carve((size_t)npad * 256 * 2);
    u16*      W1r   = (u16*)carve((size_t)64 * 128 * 2);
    u16*      W2r   = (u16*)carve((size_t)128 * 256 * 2);
    u16*      W3r   = (u16*)carve((size_t)256 * 256 * 2);
    float* S1 = (float*)carve(128 * 4); float* T1 = (float*)carve(128 * 4);
    float* S2 = (float*)carve(256 * 4); float* T2 = (float*)carve(256 * 4);
    float* S3 = (float*)carve(256 * 4); float* T3 = (float*)carve(256 * 4);
    float* psum = (float*)carve((size_t)NGRAPH * 256 * 4);
    float* pmax = (float*)carve((size_t)NGRAPH * 256 * 4);
    int*   pcnt = (int*)carve((size_t)NGRAPH * 4);
    float* z    = (float*)carve((size_t)NGRAPH * 512 * 4);
    float* z1   = (float*)carve((size_t)NGRAPH * 256 * 4);
    float* z2   = (float*)carve((size_t)NGRAPH * 128 * 4);
    float* z3   = (float*)carve((size_t)NGRAPH * 8 * 4);
    (void)ws_size; (void)n_in;

    const int BT = 256;

    detect_dtype<<<1, 64, 0, stream>>>(x, flag);
    cvt_bf_s<<<(n * 64 + BT - 1) / BT, BT, 0, stream>>>(x, xs, n, npad, flag);
    repack_w<<<(64 * 128 + BT - 1) / BT, BT, 0, stream>>>(W1, W1r, 64, 128, flag);
    repack_w<<<(128 * 256 + BT - 1) / BT, BT, 0, stream>>>(W2, W2r, 128, 256, flag);
    repack_w<<<(256 * 256 + BT - 1) / BT, BT, 0, stream>>>(W3, W3r, 256, 256, flag);
    fold_bn_all<<<3, 256, 0, stream>>>(b1, g1, be1, m1, v1, b2, g2, be2, m2, v2,
                                       b3, g3, be3, m3, v3, S1, T1, S2, T2, S3, T3, flag);

    init_csr<<<(n + BT - 1) / BT, BT, 0, stream>>>(deg_i, total, bcnt, n);
    count_deg_i<<<(E + BT - 1) / BT, BT, 0, stream>>>(dst, deg_i, E);
    reserve_rows<<<(n + BT - 1) / BT, BT, 0, stream>>>(deg_i, rowst, curs, dis, csrw, total, bcnt, n);
    bucket_prefix<<<1, 64, 0, stream>>>(bcnt, bcur);
    bucket_scatter<<<(n + BT - 1) / BT, BT, 0, stream>>>(deg_i, rowst, bcur, ninfo, n);
    scatter_edges<<<(E + BT - 1) / BT, BT, 0, stream>>>(src, dst, dis, curs, csrw, E);

    const int gblocks = (n + 63) / 64;
    const int nb64 = (n + 63) / 64;     // 64 nodes per block (16/wave x 4 waves)

    // layer 1: agg x (2 slices) -> GEMM 64->128 (+BN+ReLU), out 4-sliced
    csr_agg_s4<2><<<2 * nb64, 256, 0, stream>>>(ninfo, csrw, xs, AG, n, npad);
    mfma_gemm_bn<64, 128, 4><<<gblocks, 256, 0, stream>>>(AG, W1r, S1, T1, Hs, n, npad);

    // layer 2: agg h (4 slices) -> GEMM 128->256 (+BN+ReLU), out 8-sliced
    csr_agg_s4<4><<<4 * nb64, 256, 0, stream>>>(ninfo, csrw, Hs, AG, n, npad);
    mfma_gemm_bn<128, 256, 8><<<gblocks, 256, 0, stream>>>(AG, W2r, S2, T2, Hs, n, npad);

    // layer 3: agg h (8 slices) -> GEMM 256->256 (+BN+ReLU), out row-major
    csr_agg_s4<8><<<8 * nb64, 256, 0, stream>>>(ninfo, csrw, Hs, AG, n, npad);
    mfma_gemm_bn<256, 256, 0><<<gblocks, 256, 0, stream>>>(AG, W3r, S3, T3, H, n, npad);

    init_pool<<<(NGRAPH * 256 + BT - 1) / BT, BT, 0, stream>>>(psum, pmax, pcnt);
    const int pool_waves = (n + POOL_NC - 1) / POOL_NC;
    pool_seg<<<(pool_waves * 64 + BT - 1) / BT, BT, 0, stream>>>(H, batch, psum, pmax, pcnt, n);
    build_z<<<(NGRAPH * 256 + BT - 1) / BT, BT, 0, stream>>>(psum, pmax, pcnt, z);

    mlp_gemm<512, 256, true><<<NGRAPH, 256, 0, stream>>>(z, Wm1, bm1, z1, flag);
    mlp_gemm<256, 128, true><<<NGRAPH, 256, 0, stream>>>(z1, Wm2, bm2, z2, flag);
    mlp_gemm<128, 6, false><<<NGRAPH, 128, 0, stream>>>(z2, Wm3, bm3, z3, flag);
    write_out<<<(NGRAPH * 6 + BT - 1) / BT, BT, 0, stream>>>(z3, d_out, NGRAPH * 6, flag);
}

// Round 14
// 475.958 us; speedup vs baseline: 1.0913x; 1.0913x over previous
//
#include <hip/hip_runtime.h>
#include <hip/hip_bf16.h>
#include <hip/hip_fp16.h>

typedef __hip_bfloat16 bf16;
typedef unsigned short u16;
typedef short bfrag __attribute__((ext_vector_type(8)));   // 8 bf16 = 4 VGPRs
typedef float f32x4 __attribute__((ext_vector_type(4)));
typedef unsigned u32x2 __attribute__((ext_vector_type(2))); // native vec for nt-store

#define NGRAPH 512
#define BN_EPS 1e-5f
#define NBUCK 64

__device__ __forceinline__ float b2f(bf16 x) { return __bfloat162float(x); }
__device__ __forceinline__ float bf_lo(unsigned u) { return __uint_as_float(u << 16); }
__device__ __forceinline__ float bf_hi(unsigned u) { return __uint_as_float(u & 0xffff0000u); }
__device__ __forceinline__ u16 f2u(float v) {
    bf16 t = __float2bfloat16(v);
    u16 r; __builtin_memcpy(&r, &t, 2); return r;
}

__device__ __forceinline__ float load_f(const void* p, int i, int isbf16) {
    if (isbf16) {
        unsigned short u = ((const unsigned short*)p)[i];
        return __uint_as_float(((unsigned int)u) << 16);
    }
    return ((const float*)p)[i];
}

// ---------------- dtype detection ----------------
__global__ void detect_dtype(const void* __restrict__ x, int* __restrict__ flag) {
    int lane = threadIdx.x & 63;
    unsigned short u = ((const unsigned short*)x)[2 * lane];
    float f = __uint_as_float(((unsigned int)u) << 16);
    int crazy = (!(fabsf(f) <= 1024.0f)) ? 1 : 0;
    unsigned long long m = __ballot(crazy);
    if (threadIdx.x == 0) *flag = (m == 0ULL) ? 1 : 0;   // 1 = bf16, 0 = fp32
}

// ---------------- convert x -> bf16, slice-major [2][npad][32] -------------
__global__ void cvt_bf_s(const void* __restrict__ in, u16* __restrict__ out,
                         int n, int npad, const int* __restrict__ flag) {
    int i = blockIdx.x * blockDim.x + threadIdx.x;
    if (i >= n * 64) return;
    int node = i >> 6, f = i & 63;
    out[((size_t)(f >> 5) * npad + node) * 32 + (f & 31)] = f2u(load_f(in, i, *flag));
}

// ---------------- repack W[K][N] into MFMA B-fragment order ----------------
__global__ void repack_w(const void* __restrict__ W, u16* __restrict__ out,
                         int Kd, int Nd, const int* __restrict__ flag) {
    int t = blockIdx.x * blockDim.x + threadIdx.x;
    if (t >= Kd * Nd) return;
    int isbf = *flag;
    int j = t & 7;
    int lane = (t >> 3) & 63;
    int tile = t >> 9;
    int NT = Nd / 16;
    int nt = tile % NT, kt = tile / NT;
    int k = kt * 32 + (lane >> 4) * 8 + j;
    int nn = nt * 16 + (lane & 15);
    out[t] = f2u(load_f(W, k * Nd + nn, isbf));
}

// ---------------- all three BN foldings in one dispatch --------------------
__device__ __forceinline__ void fold_one(const void* b, const void* g, const void* be,
                                         const void* m, const void* v,
                                         float* S, float* T, int f, int isbf) {
    float bb = load_f(b, f, isbf), gg = load_f(g, f, isbf);
    float bee = load_f(be, f, isbf), mm = load_f(m, f, isbf);
    float vv = load_f(v, f, isbf);
    float s = gg * rsqrtf(vv + BN_EPS);
    S[f] = s;
    T[f] = (bb - mm) * s + bee;
}

__global__ void fold_bn_all(
    const void* b1, const void* g1, const void* be1, const void* m1, const void* v1,
    const void* b2, const void* g2, const void* be2, const void* m2, const void* v2,
    const void* b3, const void* g3, const void* be3, const void* m3, const void* v3,
    float* S1, float* T1, float* S2, float* T2, float* S3, float* T3,
    const int* __restrict__ flag) {
    int t = blockIdx.x * blockDim.x + threadIdx.x;
    int isbf = *flag;
    if (t < 128) fold_one(b1, g1, be1, m1, v1, S1, T1, t, isbf);
    else if (t < 384) fold_one(b2, g2, be2, m2, v2, S2, T2, t - 128, isbf);
    else if (t < 640) fold_one(b3, g3, be3, m3, v3, S3, T3, t - 384, isbf);
}

// ---------------- CSR build (padded segments + packed edge records) --------
__global__ void init_csr(int* __restrict__ deg, int* __restrict__ total,
                         int* __restrict__ bcnt, int n) {
    int i = blockIdx.x * blockDim.x + threadIdx.x;
    if (i < n) deg[i] = 0;
    if (i < NBUCK) bcnt[i] = 0;
    if (i == 0) *total = 0;
}

__global__ void count_deg_i(const int* __restrict__ dst, int* __restrict__ deg, int e) {
    int i = blockIdx.x * blockDim.x + threadIdx.x;
    if (i < e) atomicAdd(&deg[dst[i]], 1);
}

// Reserve 8-padded CSR segment per node; LDS degree histogram (divergent
// global atomics serialize — r9 lesson); pad entries filled here too.
__global__ void reserve_rows(const int* __restrict__ deg, int* __restrict__ row_start,
                             int* __restrict__ cursor, float* __restrict__ dis,
                             unsigned* __restrict__ csrw,
                             int* __restrict__ total, int* __restrict__ bcnt, int n) {
    __shared__ int lh[NBUCK];
    int tid = threadIdx.x;
    if (tid < NBUCK) lh[tid] = 0;
    __syncthreads();
    int i = blockIdx.x * blockDim.x + tid;
    if (i < n) {
        int d = deg[i];
        int dpad = (d + 7) & ~7;
        int s = atomicAdd(total, dpad);     // uniform address -> wave-coalesced
        row_start[i] = s;
        cursor[i] = s;
        dis[i] = rsqrtf((float)(d + 1));    // +1 self-loop
        atomicAdd(&lh[min(d, NBUCK - 1)], 1);
        unsigned val = (unsigned)(i & 0xffff);   // pad: src=self, norm=+0
        for (int k = d; k < dpad; k++) csrw[s + k] = val;
    }
    __syncthreads();
    if (tid < NBUCK) {
        int c = lh[tid];
        if (c) atomicAdd(&bcnt[tid], c);
    }
}

__global__ void bucket_prefix(const int* __restrict__ bcnt, int* __restrict__ bcur) {
    if (threadIdx.x == 0 && blockIdx.x == 0) {
        int acc = 0;
        for (int i = 0; i < NBUCK; i++) { bcur[i] = acc; acc += bcnt[i]; }
    }
}

// Ranked scatter emitting packed per-node records {node, start, deg, -}.
__global__ void bucket_scatter(const int* __restrict__ deg, const int* __restrict__ rowst,
                               int* __restrict__ bcur, uint4* __restrict__ ninfo, int n) {
    __shared__ int lh[NBUCK];
    __shared__ int lbase[NBUCK];
    int tid = threadIdx.x;
    if (tid < NBUCK) lh[tid] = 0;
    __syncthreads();
    int i = blockIdx.x * blockDim.x + tid;
    int b = 0, lr = 0;
    if (i < n) {
        b = min(deg[i], NBUCK - 1);
        lr = atomicAdd(&lh[b], 1);          // LDS local rank
    }
    __syncthreads();
    if (tid < NBUCK) {
        int c = lh[tid];
        lbase[tid] = c ? atomicAdd(&bcur[tid], c) : 0;
    }
    __syncthreads();
    if (i < n) ninfo[lbase[b] + lr] = make_uint4(i, rowst[i], deg[i], 0);
}

// Pack {u16 src, fp16 norm} per edge; norm computed once here.
__global__ void scatter_edges(const int* __restrict__ src, const int* __restrict__ dst,
                              const float* __restrict__ dis, int* __restrict__ cursor,
                              unsigned* __restrict__ csrw, int e) {
    int i = blockIdx.x * blockDim.x + threadIdx.x;
    if (i >= e) return;
    int s = src[i], dt = dst[i];
    int pos = atomicAdd(&cursor[dt], 1);
    float nw = dis[s] * dis[dt];
    unsigned short h = __half_as_ushort(__float2half(nw));
    csrw[pos] = (unsigned)(s & 0xffff) | ((unsigned)h << 16);
}

// ---------------- XCD-sliced CSR aggregation v5 ----------------------------
// r11 shape (8 lanes/node, uint2 loads, cached csrw) + double-buffered meta
// records (break the meta->feature serial chain with cached-latency loads;
// r13's nt meta loads paid HBM latency -> VALUBusy 41%->19%, dur +50%) +
// nt-store on AG (no in-kernel consumer; avoid 3.2MB/pass write-allocate).
template <int NSLICE>
__global__ __launch_bounds__(256) void csr_agg_s5(
    const uint4* __restrict__ ninfo, const unsigned* __restrict__ csrw,
    const u16* __restrict__ hs, u16* __restrict__ AG, int n, int npad) {
    constexpr int F = NSLICE * 32;
    int slice = blockIdx.x % NSLICE;
    int nb = blockIdx.x / NSLICE;
    int lane = threadIdx.x & 63;
    int wv = threadIdx.x >> 6;
    int sub = lane >> 3, ls = lane & 7;
    int oidx = nb * 32 + wv * 8 + sub;
    if (oidx >= n) return;
    uint4 nf = ninfo[oidx];                 // contiguous 16B records
    int node = (int)nf.x;
    int start = (int)nf.y;
    int d = (int)nf.z;
    int dpad = (d + 7) & ~7;
    float dd = 1.0f / (float)(d + 1);       // dis^2 for the self-loop
    const u16* __restrict__ base = hs + (size_t)slice * npad * 32;

    float a0, a1, a2, a3;
    {
        uint2 u = *(const uint2*)(base + (size_t)node * 32 + ls * 4);
        a0 = bf_lo(u.x) * dd; a1 = bf_hi(u.x) * dd;
        a2 = bf_lo(u.y) * dd; a3 = bf_hi(u.y) * dd;
    }

    const unsigned* __restrict__ ep = csrw + start;
    unsigned mc[8];
    if (dpad) {
#pragma unroll
        for (int j = 0; j < 8; j++) mc[j] = ep[j];   // broadcast in subgroup
    }
    for (int k = 0; k < dpad; k += 8) {
        unsigned mn[8];
        if (k + 8 < dpad) {
#pragma unroll
            for (int j = 0; j < 8; j++) mn[j] = ep[k + 8 + j];   // prefetch next
        }
        float w[8];
        uint2 q[8];
#pragma unroll
        for (int j = 0; j < 8; j++) {
            int s = (int)(mc[j] & 0xffffu);
            w[j] = __half2float(__ushort_as_half((unsigned short)(mc[j] >> 16)));
            q[j] = *(const uint2*)(base + (size_t)s * 32 + ls * 4);
        }
#pragma unroll
        for (int j = 0; j < 8; j++) {
            a0 += w[j] * bf_lo(q[j].x); a1 += w[j] * bf_hi(q[j].x);
            a2 += w[j] * bf_lo(q[j].y); a3 += w[j] * bf_hi(q[j].y);
        }
#pragma unroll
        for (int j = 0; j < 8; j++) mc[j] = mn[j];
    }
    u32x2 o;
    o.x = (unsigned)f2u(a0) | ((unsigned)f2u(a1) << 16);
    o.y = (unsigned)f2u(a2) | ((unsigned)f2u(a3) << 16);
    __builtin_nontemporal_store(o, (u32x2*)(AG + (size_t)node * F + slice * 32 + ls * 4));
}

// ---------------- MFMA GEMM + fused BN + ReLU ------------------------------
template <int K, int N, int NSLICE_OUT>
__global__ __launch_bounds__(256) void mfma_gemm_bn(
    const u16* __restrict__ A, const u16* __restrict__ Wrep,
    const float* __restrict__ S, const float* __restrict__ T,
    u16* __restrict__ C, int M, int npad) {
    constexpr int KP = K + 8;
    constexpr int NT = N / 16;
    constexpr int KT = K / 32;
    __shared__ u16 Alds[64 * KP];
    const int m0 = blockIdx.x * 64;
    const int tid = threadIdx.x;
    for (int c = tid; c < 64 * (K / 8); c += 256) {
        int r = c / (K / 8), kc = c % (K / 8);
        uint4 v = *(const uint4*)(A + (size_t)(m0 + r) * K + kc * 8);
        *(uint4*)(&Alds[r * KP + kc * 8]) = v;
    }
    __syncthreads();
    const int wv = tid >> 6, lane = tid & 63;
    const int mrow = lane & 15;
    const int kb = lane >> 4;
    f32x4 acc[NT];
#pragma unroll
    for (int nt = 0; nt < NT; nt++) acc[nt] = (f32x4){0.f, 0.f, 0.f, 0.f};
#pragma unroll
    for (int kt = 0; kt < KT; kt++) {
        bfrag a = *(const bfrag*)(&Alds[(wv * 16 + mrow) * KP + kt * 32 + kb * 8]);
#pragma unroll
        for (int nt = 0; nt < NT; nt++) {
            bfrag b = *(const bfrag*)(Wrep + ((size_t)(kt * NT + nt) * 64 + lane) * 8);
            acc[nt] = __builtin_amdgcn_mfma_f32_16x16x32_bf16(a, b, acc[nt], 0, 0, 0);
        }
    }
#pragma unroll
    for (int nt = 0; nt < NT; nt++) {
        int f = nt * 16 + mrow;
        float s = S[f];
        float t = T[f];
#pragma unroll
        for (int r = 0; r < 4; r++) {
            int row = m0 + wv * 16 + kb * 4 + r;
            if (row < M) {
                u16 val = f2u(fmaxf(acc[nt][r] * s + t, 0.0f));
                if (NSLICE_OUT > 0)
                    C[((size_t)(f >> 5) * npad + row) * 32 + (f & 31)] = val;
                else
                    C[(size_t)row * N + f] = val;
            }
        }
    }
}

// ---------------- pooling ----------------
__global__ void init_pool(float* __restrict__ psum, float* __restrict__ pmax,
                          int* __restrict__ pcnt) {
    int i = blockIdx.x * blockDim.x + threadIdx.x;
    if (i < NGRAPH * 256) { psum[i] = 0.f; pmax[i] = 0.f; }
    if (i < NGRAPH) pcnt[i] = 0;
}

#define POOL_NC 64
__global__ __launch_bounds__(256) void pool_seg(
    const u16* __restrict__ h, const int* __restrict__ batch,
    float* __restrict__ psum, float* __restrict__ pmax,
    int* __restrict__ pcnt, int n) {
    int wid = (int)(((size_t)blockIdx.x * blockDim.x + threadIdx.x) >> 6);
    int lane = threadIdx.x & 63;
    int n0 = wid * POOL_NC;
    if (n0 >= n) return;
    int n1 = min(n0 + POOL_NC, n);

    float sum[4] = {0.f, 0.f, 0.f, 0.f};
    float mx[4] = {0.f, 0.f, 0.f, 0.f};
    int cnt = 0;
    int gcur = batch[n0];

    uint2 u_next = *(const uint2*)(h + (size_t)n0 * 256 + lane * 4);
    int g_next = gcur;

    for (int node = n0; node < n1; node++) {
        uint2 u = u_next;
        int g = g_next;
        if (node + 1 < n1) {
            u_next = *(const uint2*)(h + (size_t)(node + 1) * 256 + lane * 4);
            g_next = batch[node + 1];
        }
        if (g != gcur) {
#pragma unroll
            for (int c = 0; c < 4; c++) {
                atomicAdd(&psum[gcur * 256 + lane * 4 + c], sum[c]);
                atomicMax((int*)&pmax[gcur * 256 + lane * 4 + c], __float_as_int(mx[c]));
                sum[c] = 0.f; mx[c] = 0.f;
            }
            if (lane == 0) atomicAdd(&pcnt[gcur], cnt);
            cnt = 0;
            gcur = g;
        }
        float v0 = bf_lo(u.x), v1 = bf_hi(u.x), v2 = bf_lo(u.y), v3 = bf_hi(u.y);
        sum[0] += v0; sum[1] += v1; sum[2] += v2; sum[3] += v3;
        mx[0] = fmaxf(mx[0], v0); mx[1] = fmaxf(mx[1], v1);
        mx[2] = fmaxf(mx[2], v2); mx[3] = fmaxf(mx[3], v3);
        cnt++;
    }
#pragma unroll
    for (int c = 0; c < 4; c++) {
        atomicAdd(&psum[gcur * 256 + lane * 4 + c], sum[c]);
        atomicMax((int*)&pmax[gcur * 256 + lane * 4 + c], __float_as_int(mx[c]));
    }
    if (lane == 0) atomicAdd(&pcnt[gcur], cnt);
}

__global__ void build_z(const float* __restrict__ psum, const float* __restrict__ pmax,
                        const int* __restrict__ pcnt, float* __restrict__ z) {
    int i = blockIdx.x * blockDim.x + threadIdx.x;
    if (i >= NGRAPH * 256) return;
    int g = i >> 8, f = i & 255;
    float c = (float)max(pcnt[g], 1);
    z[g * 512 + f] = psum[i] / c;
    z[g * 512 + 256 + f] = pmax[i];
}

// ---------------- MLP GEMM (block per row) ----------------
template <int K, int NOUT, bool GELU>
__global__ void mlp_gemm(const float* __restrict__ A, const void* __restrict__ W,
                         const void* __restrict__ bias, float* __restrict__ C,
                         const int* __restrict__ flag) {
    __shared__ float a[K];
    int row = blockIdx.x;
    for (int idx = threadIdx.x; idx < K; idx += blockDim.x) a[idx] = A[row * K + idx];
    __syncthreads();
    int col = threadIdx.x;
    if (col < NOUT) {
        int isbf = *flag;
        float acc = load_f(bias, col, isbf);
        if (isbf) {
            const bf16* w = (const bf16*)W;
            for (int k = 0; k < K; k++) acc += a[k] * b2f(w[k * NOUT + col]);
        } else {
            const float* w = (const float*)W;
            for (int k = 0; k < K; k++) acc += a[k] * w[k * NOUT + col];
        }
        if (GELU) acc = 0.5f * acc * (1.0f + erff(acc * 0.70710678118654752f));
        C[row * NOUT + col] = acc;
    }
}

__global__ void write_out(const float* __restrict__ in, void* __restrict__ out,
                          int n, const int* __restrict__ flag) {
    int i = blockIdx.x * blockDim.x + threadIdx.x;
    if (i >= n) return;
    if (*flag) ((bf16*)out)[i] = __float2bfloat16(in[i]);
    else       ((float*)out)[i] = in[i];
}

extern "C" void kernel_launch(void* const* d_in, const int* in_sizes, int n_in,
                              void* d_out, int out_size, void* d_ws, size_t ws_size,
                              hipStream_t stream) {
    const void* x     = d_in[0];
    const int*  ei    = (const int*)d_in[1];
    const int*  batch = (const int*)d_in[2];
    const void *W1 = d_in[3],  *b1 = d_in[4],  *g1 = d_in[5],  *be1 = d_in[6],  *m1 = d_in[7],  *v1 = d_in[8];
    const void *W2 = d_in[9],  *b2 = d_in[10], *g2 = d_in[11], *be2 = d_in[12], *m2 = d_in[13], *v2 = d_in[14];
    const void *W3 = d_in[15], *b3 = d_in[16], *g3 = d_in[17], *be3 = d_in[18], *m3 = d_in[19], *v3 = d_in[20];
    const void *Wm1 = d_in[21], *bm1 = d_in[22];
    const void *Wm2 = d_in[23], *bm2 = d_in[24];
    const void *Wm3 = d_in[25], *bm3 = d_in[26];

    const int n = in_sizes[0] / 64;     // 50000
    const int E = in_sizes[1] / 2;      // 800000
    const int* src = ei;
    const int* dst = ei + E;
    const int npad = (n + 63 + 64) & ~63;

    size_t off = 0;
    auto carve = [&](size_t bytes) {
        void* p = (char*)d_ws + off;
        off += (bytes + 255) & ~(size_t)255;
        return p;
    };
    int*      flag  = (int*)carve(4);
    int*      total = (int*)carve(4);
    int*      bcnt  = (int*)carve(NBUCK * 4);
    int*      bcur  = (int*)carve(NBUCK * 4);
    float*    dis   = (float*)carve((size_t)n * 4);
    int*      deg_i = (int*)carve((size_t)n * 4);
    int*      rowst = (int*)carve((size_t)n * 4);
    int*      curs  = (int*)carve((size_t)n * 4);
    uint4*    ninfo = (uint4*)carve((size_t)n * 16);
    unsigned* csrw  = (unsigned*)carve(((size_t)E + 8 * (size_t)n) * 4);
    u16*      xs    = (u16*)carve((size_t)npad * 64 * 2);
    u16*      Hs    = (u16*)carve((size_t)npad * 256 * 2);
    u16*      AG    = (u16*)carve((size_t)npad * 256 * 2);
    u16*      H     = (u16*)carve((size_t)npad * 256 * 2);
    u16*      W1r   = (u16*)carve((size_t)64 * 128 * 2);
    u16*      W2r   = (u16*)carve((size_t)128 * 256 * 2);
    u16*      W3r   = (u16*)carve((size_t)256 * 256 * 2);
    float* S1 = (float*)carve(128 * 4); float* T1 = (float*)carve(128 * 4);
    float* S2 = (float*)carve(256 * 4); float* T2 = (float*)carve(256 * 4);
    float* S3 = (float*)carve(256 * 4); float* T3 = (float*)carve(256 * 4);
    float* psum = (float*)carve((size_t)NGRAPH * 256 * 4);
    float* pmax = (float*)carve((size_t)NGRAPH * 256 * 4);
    int*   pcnt = (int*)carve((size_t)NGRAPH * 4);
    float* z    = (float*)carve((size_t)NGRAPH * 512 * 4);
    float* z1   = (float*)carve((size_t)NGRAPH * 256 * 4);
    float* z2   = (float*)carve((size_t)NGRAPH * 128 * 4);
    float* z3   = (float*)carve((size_t)NGRAPH * 8 * 4);
    (void)ws_size; (void)n_in;

    const int BT = 256;

    detect_dtype<<<1, 64, 0, stream>>>(x, flag);
    cvt_bf_s<<<(n * 64 + BT - 1) / BT, BT, 0, stream>>>(x, xs, n, npad, flag);
    repack_w<<<(64 * 128 + BT - 1) / BT, BT, 0, stream>>>(W1, W1r, 64, 128, flag);
    repack_w<<<(128 * 256 + BT - 1) / BT, BT, 0, stream>>>(W2, W2r, 128, 256, flag);
    repack_w<<<(256 * 256 + BT - 1) / BT, BT, 0, stream>>>(W3, W3r, 256, 256, flag);
    fold_bn_all<<<3, 256, 0, stream>>>(b1, g1, be1, m1, v1, b2, g2, be2, m2, v2,
                                       b3, g3, be3, m3, v3, S1, T1, S2, T2, S3, T3, flag);

    init_csr<<<(n + BT - 1) / BT, BT, 0, stream>>>(deg_i, total, bcnt, n);
    count_deg_i<<<(E + BT - 1) / BT, BT, 0, stream>>>(dst, deg_i, E);
    reserve_rows<<<(n + BT - 1) / BT, BT, 0, stream>>>(deg_i, rowst, curs, dis, csrw, total, bcnt, n);
    bucket_prefix<<<1, 64, 0, stream>>>(bcnt, bcur);
    bucket_scatter<<<(n + BT - 1) / BT, BT, 0, stream>>>(deg_i, rowst, bcur, ninfo, n);
    scatter_edges<<<(E + BT - 1) / BT, BT, 0, stream>>>(src, dst, dis, curs, csrw, E);

    const int gblocks = (n + 63) / 64;
    const int nb32 = (n + 31) / 32;     // 32 nodes per block (8/wave x 4 waves)

    // layer 1: agg x (2 slices) -> GEMM 64->128 (+BN+ReLU), out 4-sliced
    csr_agg_s5<2><<<2 * nb32, 256, 0, stream>>>(ninfo, csrw, xs, AG, n, npad);
    mfma_gemm_bn<64, 128, 4><<<gblocks, 256, 0, stream>>>(AG, W1r, S1, T1, Hs, n, npad);

    // layer 2: agg h (4 slices) -> GEMM 128->256 (+BN+ReLU), out 8-sliced
    csr_agg_s5<4><<<4 * nb32, 256, 0, stream>>>(ninfo, csrw, Hs, AG, n, npad);
    mfma_gemm_bn<128, 256, 8><<<gblocks, 256, 0, stream>>>(AG, W2r, S2, T2, Hs, n, npad);

    // layer 3: agg h (8 slices) -> GEMM 256->256 (+BN+ReLU), out row-major
    csr_agg_s5<8><<<8 * nb32, 256, 0, stream>>>(ninfo, csrw, Hs, AG, n, npad);
    mfma_gemm_bn<256, 256, 0><<<gblocks, 256, 0, stream>>>(AG, W3r, S3, T3, H, n, npad);

    init_pool<<<(NGRAPH * 256 + BT - 1) / BT, BT, 0, stream>>>(psum, pmax, pcnt);
    const int pool_waves = (n + POOL_NC - 1) / POOL_NC;
    pool_seg<<<(pool_waves * 64 + BT - 1) / BT, BT, 0, stream>>>(H, batch, psum, pmax, pcnt, n);
    build_z<<<(NGRAPH * 256 + BT - 1) / BT, BT, 0, stream>>>(psum, pmax, pcnt, z);

    mlp_gemm<512, 256, true><<<NGRAPH, 256, 0, stream>>>(z, Wm1, bm1, z1, flag);
    mlp_gemm<256, 128, true><<<NGRAPH, 256, 0, stream>>>(z1, Wm2, bm2, z2, flag);
    mlp_gemm<128, 6, false><<<NGRAPH, 128, 0, stream>>>(z2, Wm3, bm3, z3, flag);
    write_out<<<(NGRAPH * 6 + BT - 1) / BT, BT, 0, stream>>>(z3, d_out, NGRAPH * 6, flag);
}

// Round 15
// 461.313 us; speedup vs baseline: 1.1260x; 1.0317x over previous
//
#include <hip/hip_runtime.h>
#include <hip/hip_bf16.h>
#include <hip/hip_fp16.h>

typedef __hip_bfloat16 bf16;
typedef unsigned short u16;
typedef short bfrag __attribute__((ext_vector_type(8)));   // 8 bf16 = 4 VGPRs
typedef float f32x4 __attribute__((ext_vector_type(4)));
typedef unsigned u32x2 __attribute__((ext_vector_type(2))); // native vec for nt-store

#define NGRAPH 512
#define BN_EPS 1e-5f
#define NBUCK 64

__device__ __forceinline__ float b2f(bf16 x) { return __bfloat162float(x); }
__device__ __forceinline__ float bf_lo(unsigned u) { return __uint_as_float(u << 16); }
__device__ __forceinline__ float bf_hi(unsigned u) { return __uint_as_float(u & 0xffff0000u); }
__device__ __forceinline__ u16 f2u(float v) {
    bf16 t = __float2bfloat16(v);
    u16 r; __builtin_memcpy(&r, &t, 2); return r;
}

__device__ __forceinline__ float load_f(const void* p, int i, int isbf16) {
    if (isbf16) {
        unsigned short u = ((const unsigned short*)p)[i];
        return __uint_as_float(((unsigned int)u) << 16);
    }
    return ((const float*)p)[i];
}

// ---------------- dtype detection ----------------
__global__ void detect_dtype(const void* __restrict__ x, int* __restrict__ flag) {
    int lane = threadIdx.x & 63;
    unsigned short u = ((const unsigned short*)x)[2 * lane];
    float f = __uint_as_float(((unsigned int)u) << 16);
    int crazy = (!(fabsf(f) <= 1024.0f)) ? 1 : 0;
    unsigned long long m = __ballot(crazy);
    if (threadIdx.x == 0) *flag = (m == 0ULL) ? 1 : 0;   // 1 = bf16, 0 = fp32
}

// ---------------- convert x -> bf16, slice-major [2][npad][32] -------------
__global__ void cvt_bf_s(const void* __restrict__ in, u16* __restrict__ out,
                         int n, int npad, const int* __restrict__ flag) {
    int i = blockIdx.x * blockDim.x + threadIdx.x;
    if (i >= n * 64) return;
    int node = i >> 6, f = i & 63;
    out[((size_t)(f >> 5) * npad + node) * 32 + (f & 31)] = f2u(load_f(in, i, *flag));
}

// ---------------- repack W[K][N] into MFMA B-fragment order ----------------
__global__ void repack_w(const void* __restrict__ W, u16* __restrict__ out,
                         int Kd, int Nd, const int* __restrict__ flag) {
    int t = blockIdx.x * blockDim.x + threadIdx.x;
    if (t >= Kd * Nd) return;
    int isbf = *flag;
    int j = t & 7;
    int lane = (t >> 3) & 63;
    int tile = t >> 9;
    int NT = Nd / 16;
    int nt = tile % NT, kt = tile / NT;
    int k = kt * 32 + (lane >> 4) * 8 + j;
    int nn = nt * 16 + (lane & 15);
    out[t] = f2u(load_f(W, k * Nd + nn, isbf));
}

// ---------------- all three BN foldings in one dispatch --------------------
__device__ __forceinline__ void fold_one(const void* b, const void* g, const void* be,
                                         const void* m, const void* v,
                                         float* S, float* T, int f, int isbf) {
    float bb = load_f(b, f, isbf), gg = load_f(g, f, isbf);
    float bee = load_f(be, f, isbf), mm = load_f(m, f, isbf);
    float vv = load_f(v, f, isbf);
    float s = gg * rsqrtf(vv + BN_EPS);
    S[f] = s;
    T[f] = (bb - mm) * s + bee;
}

__global__ void fold_bn_all(
    const void* b1, const void* g1, const void* be1, const void* m1, const void* v1,
    const void* b2, const void* g2, const void* be2, const void* m2, const void* v2,
    const void* b3, const void* g3, const void* be3, const void* m3, const void* v3,
    float* S1, float* T1, float* S2, float* T2, float* S3, float* T3,
    const int* __restrict__ flag) {
    int t = blockIdx.x * blockDim.x + threadIdx.x;
    int isbf = *flag;
    if (t < 128) fold_one(b1, g1, be1, m1, v1, S1, T1, t, isbf);
    else if (t < 384) fold_one(b2, g2, be2, m2, v2, S2, T2, t - 128, isbf);
    else if (t < 640) fold_one(b3, g3, be3, m3, v3, S3, T3, t - 384, isbf);
}

// ---------------- CSR build (padded segments + packed edge records) --------
__global__ void init_csr(int* __restrict__ deg, int* __restrict__ total,
                         int* __restrict__ bcnt, int n) {
    int i = blockIdx.x * blockDim.x + threadIdx.x;
    if (i < n) deg[i] = 0;
    if (i < NBUCK) bcnt[i] = 0;
    if (i == 0) *total = 0;
}

__global__ void count_deg_i(const int* __restrict__ dst, int* __restrict__ deg, int e) {
    int i = blockIdx.x * blockDim.x + threadIdx.x;
    if (i < e) atomicAdd(&deg[dst[i]], 1);
}

// Reserve 8-padded CSR segment per node; LDS degree histogram (divergent
// global atomics serialize — r9 lesson); pad entries filled here too.
__global__ void reserve_rows(const int* __restrict__ deg, int* __restrict__ row_start,
                             int* __restrict__ cursor, float* __restrict__ dis,
                             unsigned* __restrict__ csrw,
                             int* __restrict__ total, int* __restrict__ bcnt, int n) {
    __shared__ int lh[NBUCK];
    int tid = threadIdx.x;
    if (tid < NBUCK) lh[tid] = 0;
    __syncthreads();
    int i = blockIdx.x * blockDim.x + tid;
    if (i < n) {
        int d = deg[i];
        int dpad = (d + 7) & ~7;
        int s = atomicAdd(total, dpad);     // uniform address -> wave-coalesced
        row_start[i] = s;
        cursor[i] = s;
        dis[i] = rsqrtf((float)(d + 1));    // +1 self-loop
        atomicAdd(&lh[min(d, NBUCK - 1)], 1);
        unsigned val = (unsigned)(i & 0xffff);   // pad: src=self, norm=+0
        for (int k = d; k < dpad; k++) csrw[s + k] = val;
    }
    __syncthreads();
    if (tid < NBUCK) {
        int c = lh[tid];
        if (c) atomicAdd(&bcnt[tid], c);
    }
}

__global__ void bucket_prefix(const int* __restrict__ bcnt, int* __restrict__ bcur) {
    if (threadIdx.x == 0 && blockIdx.x == 0) {
        int acc = 0;
        for (int i = 0; i < NBUCK; i++) { bcur[i] = acc; acc += bcnt[i]; }
    }
}

// Ranked scatter emitting packed per-node records {node, start, deg, -}.
__global__ void bucket_scatter(const int* __restrict__ deg, const int* __restrict__ rowst,
                               int* __restrict__ bcur, uint4* __restrict__ ninfo, int n) {
    __shared__ int lh[NBUCK];
    __shared__ int lbase[NBUCK];
    int tid = threadIdx.x;
    if (tid < NBUCK) lh[tid] = 0;
    __syncthreads();
    int i = blockIdx.x * blockDim.x + tid;
    int b = 0, lr = 0;
    if (i < n) {
        b = min(deg[i], NBUCK - 1);
        lr = atomicAdd(&lh[b], 1);          // LDS local rank
    }
    __syncthreads();
    if (tid < NBUCK) {
        int c = lh[tid];
        lbase[tid] = c ? atomicAdd(&bcur[tid], c) : 0;
    }
    __syncthreads();
    if (i < n) ninfo[lbase[b] + lr] = make_uint4(i, rowst[i], deg[i], 0);
}

// Pack {u16 src, fp16 norm} per edge; norm computed once here.
__global__ void scatter_edges(const int* __restrict__ src, const int* __restrict__ dst,
                              const float* __restrict__ dis, int* __restrict__ cursor,
                              unsigned* __restrict__ csrw, int e) {
    int i = blockIdx.x * blockDim.x + threadIdx.x;
    if (i >= e) return;
    int s = src[i], dt = dst[i];
    int pos = atomicAdd(&cursor[dt], 1);
    float nw = dis[s] * dis[dt];
    unsigned short h = __half_as_ushort(__float2half(nw));
    csrw[pos] = (unsigned)(s & 0xffff) | ((unsigned)h << 16);
}

// ---------------- XCD-sliced CSR aggregation v5 (r14, unchanged) -----------
template <int NSLICE>
__global__ __launch_bounds__(256) void csr_agg_s5(
    const uint4* __restrict__ ninfo, const unsigned* __restrict__ csrw,
    const u16* __restrict__ hs, u16* __restrict__ AG, int n, int npad) {
    constexpr int F = NSLICE * 32;
    int slice = blockIdx.x % NSLICE;
    int nb = blockIdx.x / NSLICE;
    int lane = threadIdx.x & 63;
    int wv = threadIdx.x >> 6;
    int sub = lane >> 3, ls = lane & 7;
    int oidx = nb * 32 + wv * 8 + sub;
    if (oidx >= n) return;
    uint4 nf = ninfo[oidx];
    int node = (int)nf.x;
    int start = (int)nf.y;
    int d = (int)nf.z;
    int dpad = (d + 7) & ~7;
    float dd = 1.0f / (float)(d + 1);
    const u16* __restrict__ base = hs + (size_t)slice * npad * 32;

    float a0, a1, a2, a3;
    {
        uint2 u = *(const uint2*)(base + (size_t)node * 32 + ls * 4);
        a0 = bf_lo(u.x) * dd; a1 = bf_hi(u.x) * dd;
        a2 = bf_lo(u.y) * dd; a3 = bf_hi(u.y) * dd;
    }

    const unsigned* __restrict__ ep = csrw + start;
    unsigned mc[8];
    if (dpad) {
#pragma unroll
        for (int j = 0; j < 8; j++) mc[j] = ep[j];
    }
    for (int k = 0; k < dpad; k += 8) {
        unsigned mn[8];
        if (k + 8 < dpad) {
#pragma unroll
            for (int j = 0; j < 8; j++) mn[j] = ep[k + 8 + j];
        }
        float w[8];
        uint2 q[8];
#pragma unroll
        for (int j = 0; j < 8; j++) {
            int s = (int)(mc[j] & 0xffffu);
            w[j] = __half2float(__ushort_as_half((unsigned short)(mc[j] >> 16)));
            q[j] = *(const uint2*)(base + (size_t)s * 32 + ls * 4);
        }
#pragma unroll
        for (int j = 0; j < 8; j++) {
            a0 += w[j] * bf_lo(q[j].x); a1 += w[j] * bf_hi(q[j].x);
            a2 += w[j] * bf_lo(q[j].y); a3 += w[j] * bf_hi(q[j].y);
        }
#pragma unroll
        for (int j = 0; j < 8; j++) mc[j] = mn[j];
    }
    u32x2 o;
    o.x = (unsigned)f2u(a0) | ((unsigned)f2u(a1) << 16);
    o.y = (unsigned)f2u(a2) | ((unsigned)f2u(a3) << 16);
    __builtin_nontemporal_store(o, (u32x2*)(AG + (size_t)node * F + slice * 32 + ls * 4));
}

// ---------------- MFMA GEMM, register-resident B + fused BN + ReLU ---------
// N split into NT/NSUB chunks; a wave preloads its KT*NSUB B-fragments into
// VGPRs once (<=32 frags = 128 VGPRs), so the K-loop is ds_read + MFMA only
// (r14 showed the per-MFMA global b-load stalling both pipes at 4%/5%).
template <int K, int N, int NSUB, int NSLICE_OUT>
__global__ __launch_bounds__(256) void mfma_gemm_rb(
    const u16* __restrict__ A, const u16* __restrict__ Wrep,
    const float* __restrict__ S, const float* __restrict__ T,
    u16* __restrict__ C, int M, int npad) {
    constexpr int KP = K + 8;
    constexpr int NT = N / 16;
    constexpr int KT = K / 32;
    constexpr int NSPLIT = NT / NSUB;
    __shared__ u16 Alds[64 * KP];
    const int mt = blockIdx.x / NSPLIT;
    const int ns = blockIdx.x - mt * NSPLIT;
    const int m0 = mt * 64;
    const int tid = threadIdx.x;
    const int lane = tid & 63;
    const int wv = tid >> 6;

    // preload B fragments (identical across waves; L2-resident W)
    bfrag breg[KT * NSUB];
#pragma unroll
    for (int kt = 0; kt < KT; kt++)
#pragma unroll
        for (int j = 0; j < NSUB; j++)
            breg[kt * NSUB + j] = *(const bfrag*)(Wrep +
                ((size_t)(kt * NT + ns * NSUB + j) * 64 + lane) * 8);

    // stage A tile
    for (int c = tid; c < 64 * (K / 8); c += 256) {
        int r = c / (K / 8), kc = c % (K / 8);
        uint4 v = *(const uint4*)(A + (size_t)(m0 + r) * K + kc * 8);
        *(uint4*)(&Alds[r * KP + kc * 8]) = v;
    }
    __syncthreads();

    const int mrow = lane & 15;
    const int kb = lane >> 4;
    f32x4 acc[NSUB];
#pragma unroll
    for (int j = 0; j < NSUB; j++) acc[j] = (f32x4){0.f, 0.f, 0.f, 0.f};
#pragma unroll
    for (int kt = 0; kt < KT; kt++) {
        bfrag a = *(const bfrag*)(&Alds[(wv * 16 + mrow) * KP + kt * 32 + kb * 8]);
#pragma unroll
        for (int j = 0; j < NSUB; j++)
            acc[j] = __builtin_amdgcn_mfma_f32_16x16x32_bf16(a, breg[kt * NSUB + j], acc[j], 0, 0, 0);
    }
#pragma unroll
    for (int j = 0; j < NSUB; j++) {
        int f = (ns * NSUB + j) * 16 + mrow;
        float s = S[f];
        float t = T[f];
#pragma unroll
        for (int r = 0; r < 4; r++) {
            int row = m0 + wv * 16 + kb * 4 + r;
            if (row < M) {
                u16 val = f2u(fmaxf(acc[j][r] * s + t, 0.0f));
                if (NSLICE_OUT > 0)
                    C[((size_t)(f >> 5) * npad + row) * 32 + (f & 31)] = val;
                else
                    C[(size_t)row * N + f] = val;
            }
        }
    }
}

// ---------------- pooling ----------------
__global__ void init_pool(float* __restrict__ psum, float* __restrict__ pmax,
                          int* __restrict__ pcnt) {
    int i = blockIdx.x * blockDim.x + threadIdx.x;
    if (i < NGRAPH * 256) { psum[i] = 0.f; pmax[i] = 0.f; }
    if (i < NGRAPH) pcnt[i] = 0;
}

#define POOL_NC 64
__global__ __launch_bounds__(256) void pool_seg(
    const u16* __restrict__ h, const int* __restrict__ batch,
    float* __restrict__ psum, float* __restrict__ pmax,
    int* __restrict__ pcnt, int n) {
    int wid = (int)(((size_t)blockIdx.x * blockDim.x + threadIdx.x) >> 6);
    int lane = threadIdx.x & 63;
    int n0 = wid * POOL_NC;
    if (n0 >= n) return;
    int n1 = min(n0 + POOL_NC, n);

    float sum[4] = {0.f, 0.f, 0.f, 0.f};
    float mx[4] = {0.f, 0.f, 0.f, 0.f};
    int cnt = 0;
    int gcur = batch[n0];

    uint2 u_next = *(const uint2*)(h + (size_t)n0 * 256 + lane * 4);
    int g_next = gcur;

    for (int node = n0; node < n1; node++) {
        uint2 u = u_next;
        int g = g_next;
        if (node + 1 < n1) {
            u_next = *(const uint2*)(h + (size_t)(node + 1) * 256 + lane * 4);
            g_next = batch[node + 1];
        }
        if (g != gcur) {
#pragma unroll
            for (int c = 0; c < 4; c++) {
                atomicAdd(&psum[gcur * 256 + lane * 4 + c], sum[c]);
                atomicMax((int*)&pmax[gcur * 256 + lane * 4 + c], __float_as_int(mx[c]));
                sum[c] = 0.f; mx[c] = 0.f;
            }
            if (lane == 0) atomicAdd(&pcnt[gcur], cnt);
            cnt = 0;
            gcur = g;
        }
        float v0 = bf_lo(u.x), v1 = bf_hi(u.x), v2 = bf_lo(u.y), v3 = bf_hi(u.y);
        sum[0] += v0; sum[1] += v1; sum[2] += v2; sum[3] += v3;
        mx[0] = fmaxf(mx[0], v0); mx[1] = fmaxf(mx[1], v1);
        mx[2] = fmaxf(mx[2], v2); mx[3] = fmaxf(mx[3], v3);
        cnt++;
    }
#pragma unroll
    for (int c = 0; c < 4; c++) {
        atomicAdd(&psum[gcur * 256 + lane * 4 + c], sum[c]);
        atomicMax((int*)&pmax[gcur * 256 + lane * 4 + c], __float_as_int(mx[c]));
    }
    if (lane == 0) atomicAdd(&pcnt[gcur], cnt);
}

__global__ void build_z(const float* __restrict__ psum, const float* __restrict__ pmax,
                        const int* __restrict__ pcnt, float* __restrict__ z) {
    int i = blockIdx.x * blockDim.x + threadIdx.x;
    if (i >= NGRAPH * 256) return;
    int g = i >> 8, f = i & 255;
    float c = (float)max(pcnt[g], 1);
    z[g * 512 + f] = psum[i] / c;
    z[g * 512 + 256 + f] = pmax[i];
}

// ---------------- MLP GEMM (block per row) ----------------
template <int K, int NOUT, bool GELU>
__global__ void mlp_gemm(const float* __restrict__ A, const void* __restrict__ W,
                         const void* __restrict__ bias, float* __restrict__ C,
                         const int* __restrict__ flag) {
    __shared__ float a[K];
    int row = blockIdx.x;
    for (int idx = threadIdx.x; idx < K; idx += blockDim.x) a[idx] = A[row * K + idx];
    __syncthreads();
    int col = threadIdx.x;
    if (col < NOUT) {
        int isbf = *flag;
        float acc = load_f(bias, col, isbf);
        if (isbf) {
            const bf16* w = (const bf16*)W;
            for (int k = 0; k < K; k++) acc += a[k] * b2f(w[k * NOUT + col]);
        } else {
            const float* w = (const float*)W;
            for (int k = 0; k < K; k++) acc += a[k] * w[k * NOUT + col];
        }
        if (GELU) acc = 0.5f * acc * (1.0f + erff(acc * 0.70710678118654752f));
        C[row * NOUT + col] = acc;
    }
}

__global__ void write_out(const float* __restrict__ in, void* __restrict__ out,
                          int n, const int* __restrict__ flag) {
    int i = blockIdx.x * blockDim.x + threadIdx.x;
    if (i >= n) return;
    if (*flag) ((bf16*)out)[i] = __float2bfloat16(in[i]);
    else       ((float*)out)[i] = in[i];
}

extern "C" void kernel_launch(void* const* d_in, const int* in_sizes, int n_in,
                              void* d_out, int out_size, void* d_ws, size_t ws_size,
                              hipStream_t stream) {
    const void* x     = d_in[0];
    const int*  ei    = (const int*)d_in[1];
    const int*  batch = (const int*)d_in[2];
    const void *W1 = d_in[3],  *b1 = d_in[4],  *g1 = d_in[5],  *be1 = d_in[6],  *m1 = d_in[7],  *v1 = d_in[8];
    const void *W2 = d_in[9],  *b2 = d_in[10], *g2 = d_in[11], *be2 = d_in[12], *m2 = d_in[13], *v2 = d_in[14];
    const void *W3 = d_in[15], *b3 = d_in[16], *g3 = d_in[17], *be3 = d_in[18], *m3 = d_in[19], *v3 = d_in[20];
    const void *Wm1 = d_in[21], *bm1 = d_in[22];
    const void *Wm2 = d_in[23], *bm2 = d_in[24];
    const void *Wm3 = d_in[25], *bm3 = d_in[26];

    const int n = in_sizes[0] / 64;     // 50000
    const int E = in_sizes[1] / 2;      // 800000
    const int* src = ei;
    const int* dst = ei + E;
    const int npad = (n + 63 + 64) & ~63;

    size_t off = 0;
    auto carve = [&](size_t bytes) {
        void* p = (char*)d_ws + off;
        off += (bytes + 255) & ~(size_t)255;
        return p;
    };
    int*      flag  = (int*)carve(4);
    int*      total = (int*)carve(4);
    int*      bcnt  = (int*)carve(NBUCK * 4);
    int*      bcur  = (int*)carve(NBUCK * 4);
    float*    dis   = (float*)carve((size_t)n * 4);
    int*      deg_i = (int*)carve((size_t)n * 4);
    int*      rowst = (int*)carve((size_t)n * 4);
    int*      curs  = (int*)carve((size_t)n * 4);
    uint4*    ninfo = (uint4*)carve((size_t)n * 16);
    unsigned* csrw  = (unsigned*)carve(((size_t)E + 8 * (size_t)n) * 4);
    u16*      xs    = (u16*)carve((size_t)npad * 64 * 2);
    u16*      Hs    = (u16*)carve((size_t)npad * 256 * 2);
    u16*      AG    = (u16*)carve((size_t)npad * 256 * 2);
    u16*      H     = (u16*)carve((size_t)npad * 256 * 2);
    u16*      W1r   = (u16*)carve((size_t)64 * 128 * 2);
    u16*      W2r   = (u16*)carve((size_t)128 * 256 * 2);
    u16*      W3r   = (u16*)carve((size_t)256 * 256 * 2);
    float* S1 = (float*)carve(128 * 4); float* T1 = (float*)carve(128 * 4);
    float* S2 = (float*)carve(256 * 4); float* T2 = (float*)carve(256 * 4);
    float* S3 = (float*)carve(256 * 4); float* T3 = (float*)carve(256 * 4);
    float* psum = (float*)carve((size_t)NGRAPH * 256 * 4);
    float* pmax = (float*)carve((size_t)NGRAPH * 256 * 4);
    int*   pcnt = (int*)carve((size_t)NGRAPH * 4);
    float* z    = (float*)carve((size_t)NGRAPH * 512 * 4);
    float* z1   = (float*)carve((size_t)NGRAPH * 256 * 4);
    float* z2   = (float*)carve((size_t)NGRAPH * 128 * 4);
    float* z3   = (float*)carve((size_t)NGRAPH * 8 * 4);
    (void)ws_size; (void)n_in;

    const int BT = 256;

    detect_dtype<<<1, 64, 0, stream>>>(x, flag);
    cvt_bf_s<<<(n * 64 + BT - 1) / BT, BT, 0, stream>>>(x, xs, n, npad, flag);
    repack_w<<<(64 * 128 + BT - 1) / BT, BT, 0, stream>>>(W1, W1r, 64, 128, flag);
    repack_w<<<(128 * 256 + BT - 1) / BT, BT, 0, stream>>>(W2, W2r, 128, 256, flag);
    repack_w<<<(256 * 256 + BT - 1) / BT, BT, 0, stream>>>(W3, W3r, 256, 256, flag);
    fold_bn_all<<<3, 256, 0, stream>>>(b1, g1, be1, m1, v1, b2, g2, be2, m2, v2,
                                       b3, g3, be3, m3, v3, S1, T1, S2, T2, S3, T3, flag);

    init_csr<<<(n + BT - 1) / BT, BT, 0, stream>>>(deg_i, total, bcnt, n);
    count_deg_i<<<(E + BT - 1) / BT, BT, 0, stream>>>(dst, deg_i, E);
    reserve_rows<<<(n + BT - 1) / BT, BT, 0, stream>>>(deg_i, rowst, curs, dis, csrw, total, bcnt, n);
    bucket_prefix<<<1, 64, 0, stream>>>(bcnt, bcur);
    bucket_scatter<<<(n + BT - 1) / BT, BT, 0, stream>>>(deg_i, rowst, bcur, ninfo, n);
    scatter_edges<<<(E + BT - 1) / BT, BT, 0, stream>>>(src, dst, dis, curs, csrw, E);

    const int gblocks = (n + 63) / 64;
    const int nb32 = (n + 31) / 32;     // agg: 32 nodes per block

    // layer 1: agg x (2 slices) -> GEMM 64->128 (+BN+ReLU), out 4-sliced
    csr_agg_s5<2><<<2 * nb32, 256, 0, stream>>>(ninfo, csrw, xs, AG, n, npad);
    mfma_gemm_rb<64, 128, 8, 4><<<gblocks, 256, 0, stream>>>(AG, W1r, S1, T1, Hs, n, npad);

    // layer 2: agg h (4 slices) -> GEMM 128->256 (+BN+ReLU), out 8-sliced
    csr_agg_s5<4><<<4 * nb32, 256, 0, stream>>>(ninfo, csrw, Hs, AG, n, npad);
    mfma_gemm_rb<128, 256, 4, 8><<<gblocks * 4, 256, 0, stream>>>(AG, W2r, S2, T2, Hs, n, npad);

    // layer 3: agg h (8 slices) -> GEMM 256->256 (+BN+ReLU), out row-major
    csr_agg_s5<8><<<8 * nb32, 256, 0, stream>>>(ninfo, csrw, Hs, AG, n, npad);
    mfma_gemm_rb<256, 256, 4, 0><<<gblocks * 4, 256, 0, stream>>>(AG, W3r, S3, T3, H, n, npad);

    init_pool<<<(NGRAPH * 256 + BT - 1) / BT, BT, 0, stream>>>(psum, pmax, pcnt);
    const int pool_waves = (n + POOL_NC - 1) / POOL_NC;
    pool_seg<<<(pool_waves * 64 + BT - 1) / BT, BT, 0, stream>>>(H, batch, psum, pmax, pcnt, n);
    build_z<<<(NGRAPH * 256 + BT - 1) / BT, BT, 0, stream>>>(psum, pmax, pcnt, z);

    mlp_gemm<512, 256, true><<<NGRAPH, 256, 0, stream>>>(z, Wm1, bm1, z1, flag);
    mlp_gemm<256, 128, true><<<NGRAPH, 256, 0, stream>>>(z1, Wm2, bm2, z2, flag);
    mlp_gemm<128, 6, false><<<NGRAPH, 128, 0, stream>>>(z2, Wm3, bm3, z3, flag);
    write_out<<<(NGRAPH * 6 + BT - 1) / BT, BT, 0, stream>>>(z3, d_out, NGRAPH * 6, flag);
}